// Round 11
// baseline (1060.316 us; speedup 1.0000x reference)
//
#include <hip/hip_runtime.h>

#define SEQ 2048
#define NB 4
#define NBH 32

typedef __attribute__((ext_vector_type(8))) short bf16x8;
typedef __attribute__((ext_vector_type(4))) float f32x4;
#define MFMA __builtin_amdgcn_mfma_f32_16x16x32_bf16

// ---- ws byte offsets ----
#define OFF_VT   0ull            // Vt bf16 [32*64][2048] (8MB)
#define OFF_QB   8388608ull      // Q bf16 (8MB), contiguous with K,V for fused QKV
#define OFF_KB   16777216ull     // K bf16 (8MB); reused as gated bf16 after attn
#define OFF_VB   25165824ull     // V bf16 (8MB); reused as attended bf16 after vtrans
#define OFF_ATTF 33554432ull     // attended f32 (16MB)
#define OFF_WQT  50331648ull     // 5 transposed bf16 weights, 512KB each, contiguous
#define OFF_BCAT 52953088ull     // 1536 f32 concat bias
#define OFF_TS   52959232ull     // 3 f32 trust scalars
#define OUT_ATTN 4194304ull      // float offset of attn within d_out
#define MATSTR   (8192ull*512ull)

__device__ __forceinline__ unsigned short f2b(float f) {
  union { float f; unsigned u; } v; v.f = f;
  unsigned r = v.u + 0x7FFFu + ((v.u >> 16) & 1u);
  return (unsigned short)(r >> 16);
}
__device__ __forceinline__ float b2f(unsigned v16) {
  union { unsigned u; float f; } v; v.u = v16 << 16; return v.f;
}
__device__ __forceinline__ float sigm(float x) { return 1.0f / (1.0f + __expf(-x)); }

// ---------------------------------------------------------------------------
// prep: trust scalars (a=Wt.Wt, b=Wt.bt, c=bt.bt) + concat bias [bq|bk|bv]
// ---------------------------------------------------------------------------
__global__ __launch_bounds__(512) void k_prep(
    const float* __restrict__ Wt, const float* __restrict__ bt,
    const float* __restrict__ bq, const float* __restrict__ bk,
    const float* __restrict__ bv, float* __restrict__ bcat,
    float* __restrict__ ts) {
  const int t = threadIdx.x;
  if (t < 64) {
    float w = Wt[t], b = bt[t];
    float a = w * w, ab = w * b, c = b * b;
    #pragma unroll
    for (int off = 32; off; off >>= 1) {
      a  += __shfl_down(a, off);
      ab += __shfl_down(ab, off);
      c  += __shfl_down(c, off);
    }
    if (t == 0) { ts[0] = a; ts[1] = ab; ts[2] = c; }
  }
  bcat[t] = bq[t]; bcat[512 + t] = bk[t]; bcat[1024 + t] = bv[t];
}

// ---------------------------------------------------------------------------
// W [512][512] fp32 -> Wt [n][k] bf16 (transpose + convert)
// ---------------------------------------------------------------------------
__global__ __launch_bounds__(256) void k_wtrans(const float* __restrict__ W,
                                                unsigned short* __restrict__ Wt) {
  __shared__ unsigned short tile[64][74];
  const int k0 = blockIdx.x * 64, n0 = blockIdx.y * 64, t = threadIdx.x;
  const int rr = t >> 4, c4 = (t & 15) * 4;
  #pragma unroll
  for (int rep = 0; rep < 4; rep++) {
    const int r = rr + rep * 16;
    float4 v = *(const float4*)(W + (size_t)(k0 + r) * 512 + n0 + c4);
    tile[c4][r] = f2b(v.x); tile[c4 + 1][r] = f2b(v.y);
    tile[c4 + 2][r] = f2b(v.z); tile[c4 + 3][r] = f2b(v.w);
  }
  __syncthreads();
  #pragma unroll
  for (int rep = 0; rep < 4; rep++) {
    const int n = rr + rep * 16;
    const unsigned short* p = &tile[n][c4];
    uint2 o;
    o.x = (unsigned)p[0] | ((unsigned)p[1] << 16);
    o.y = (unsigned)p[2] | ((unsigned)p[3] << 16);
    *(uint2*)(Wt + (size_t)(n0 + n) * 512 + k0 + c4) = o;
  }
}

// ---------------------------------------------------------------------------
// V bf16 [8192][512] -> Vt bf16 [bh*64 + d][2048]
// ---------------------------------------------------------------------------
__global__ __launch_bounds__(256) void k_vtrans(const unsigned short* __restrict__ Vb,
                                                unsigned short* __restrict__ Vt) {
  __shared__ unsigned short tile[64][74];
  const int s0 = blockIdx.x * 64;
  const int bh = blockIdx.y, b = bh >> 3, h = bh & 7;
  const int t = threadIdx.x, rr = t >> 4, c4 = (t & 15) * 4;
  #pragma unroll
  for (int rep = 0; rep < 4; rep++) {
    const int r = rr + rep * 16;
    uint2 v = *(const uint2*)(Vb + (size_t)(b * SEQ + s0 + r) * 512 + h * 64 + c4);
    tile[c4][r] = v.x & 0xffff; tile[c4 + 1][r] = v.x >> 16;
    tile[c4 + 2][r] = v.y & 0xffff; tile[c4 + 3][r] = v.y >> 16;
  }
  __syncthreads();
  #pragma unroll
  for (int rep = 0; rep < 4; rep++) {
    const int d = rr + rep * 16;
    const unsigned short* p = &tile[d][c4];
    uint2 o;
    o.x = (unsigned)p[0] | ((unsigned)p[1] << 16);
    o.y = (unsigned)p[2] | ((unsigned)p[3] << 16);
    *(uint2*)(Vt + (size_t)(bh * 64 + d) * SEQ + s0 + c4) = o;
  }
}

// ---------------------------------------------------------------------------
// MFMA GEMM 64x128 tile, BK=64, 256 thr (4 waves 2x2), K=512.
// mode 0: A = x f32 (cvt inline); out = bf16(C+bias) routed to Q|K|V by n/512
// mode 1: A = attb bf16; out = bf16(Afp * sigm(C+bias+trust[m]*wg512[n]))
// mode 2: A = gated bf16; out = f32(C+bias)
// Epilogue: LDS-bounce (union with staging) -> coalesced vector stores.
// ---------------------------------------------------------------------------
__global__ __launch_bounds__(256) void k_gemm(
    const float* __restrict__ Af, const unsigned short* __restrict__ Ab,
    const unsigned short* __restrict__ Bt, const float* __restrict__ bcat,
    const float* __restrict__ wg512, const float* __restrict__ trust,
    const float* __restrict__ Afp, unsigned short* __restrict__ obf,
    float* __restrict__ ofp, int mode) {
  __shared__ union SU {
    struct { unsigned short As[8][64][8]; unsigned short Bs[8][128][8]; } s;
    float ct[64][66];
  } u;
  const int t = threadIdx.x;
  const int m0 = blockIdx.x * 64, n0 = blockIdx.y * 128;
  const int w4 = t >> 6, lane = t & 63, g = lane >> 4, ln = lane & 15;
  const int wm = w4 >> 1, wn = w4 & 1;

  f32x4 acc[2][4];
  #pragma unroll
  for (int i = 0; i < 2; i++)
    #pragma unroll
    for (int j = 0; j < 4; j++) acc[i][j] = (f32x4){0.f, 0.f, 0.f, 0.f};

  const int am = t & 63, akk = t >> 6;       // A: row am, k-octets akk, akk+4
  const int bn = t & 127, bk0 = t >> 7;      // B: row bn, k-octets bk0+2q

  #pragma unroll 1
  for (int k0 = 0; k0 < 512; k0 += 64) {
    __syncthreads();
    if (mode == 0) {
      const float* ap = Af + (size_t)(m0 + am) * 512 + k0 + akk * 8;
      float4 a0 = *(const float4*)ap,        a1 = *(const float4*)(ap + 4);
      float4 a2 = *(const float4*)(ap + 32), a3 = *(const float4*)(ap + 36);
      uint4 c0, c1;
      c0.x = (unsigned)f2b(a0.x) | ((unsigned)f2b(a0.y) << 16);
      c0.y = (unsigned)f2b(a0.z) | ((unsigned)f2b(a0.w) << 16);
      c0.z = (unsigned)f2b(a1.x) | ((unsigned)f2b(a1.y) << 16);
      c0.w = (unsigned)f2b(a1.z) | ((unsigned)f2b(a1.w) << 16);
      c1.x = (unsigned)f2b(a2.x) | ((unsigned)f2b(a2.y) << 16);
      c1.y = (unsigned)f2b(a2.z) | ((unsigned)f2b(a2.w) << 16);
      c1.z = (unsigned)f2b(a3.x) | ((unsigned)f2b(a3.y) << 16);
      c1.w = (unsigned)f2b(a3.z) | ((unsigned)f2b(a3.w) << 16);
      *(uint4*)&u.s.As[akk][am][0]     = c0;
      *(uint4*)&u.s.As[akk + 4][am][0] = c1;
    } else {
      const unsigned short* ap = Ab + (size_t)(m0 + am) * 512 + k0 + akk * 8;
      *(uint4*)&u.s.As[akk][am][0]     = *(const uint4*)ap;
      *(uint4*)&u.s.As[akk + 4][am][0] = *(const uint4*)(ap + 32);
    }
    {
      const unsigned short* bp = Bt + (size_t)(n0 + bn) * 512 + k0 + bk0 * 8;
      #pragma unroll
      for (int qq = 0; qq < 4; qq++)
        *(uint4*)&u.s.Bs[bk0 + 2 * qq][bn][0] = *(const uint4*)(bp + qq * 16);
    }
    __syncthreads();
    #pragma unroll
    for (int ks = 0; ks < 2; ks++) {
      bf16x8 af[2], bfr[4];
      #pragma unroll
      for (int i = 0; i < 2; i++)
        af[i] = *(const bf16x8*)&u.s.As[ks * 4 + g][wm * 32 + i * 16 + ln][0];
      #pragma unroll
      for (int j = 0; j < 4; j++)
        bfr[j] = *(const bf16x8*)&u.s.Bs[ks * 4 + g][wn * 64 + j * 16 + ln][0];
      #pragma unroll
      for (int i = 0; i < 2; i++)
        #pragma unroll
        for (int j = 0; j < 4; j++)
          acc[i][j] = MFMA(af[i], bfr[j], acc[i][j], 0, 0, 0);
    }
  }

  // ---- LDS-bounce epilogue: two 64x64 halves ----
  float bj[4];
  #pragma unroll
  for (int j = 0; j < 4; j++) bj[j] = bcat[n0 + wn * 64 + j * 16 + ln];

  #pragma unroll 1
  for (int h = 0; h < 2; h++) {
    __syncthreads();
    if (wn == h) {
      #pragma unroll
      for (int i = 0; i < 2; i++)
        #pragma unroll
        for (int j = 0; j < 4; j++)
          #pragma unroll
          for (int r = 0; r < 4; r++)
            u.ct[wm * 32 + i * 16 + g * 4 + r][j * 16 + ln] = acc[i][j][r] + bj[j];
    }
    __syncthreads();
    {
      const int row = t >> 2, c0 = (t & 3) << 4;
      const int m = m0 + row;
      float v[16];
      *(float4*)(v)      = *(const float4*)&u.ct[row][c0];
      *(float4*)(v + 4)  = *(const float4*)&u.ct[row][c0 + 4];
      *(float4*)(v + 8)  = *(const float4*)&u.ct[row][c0 + 8];
      *(float4*)(v + 12) = *(const float4*)&u.ct[row][c0 + 12];
      if (mode == 0) {
        const int ncg = n0 + h * 64 + c0;
        const int mat = ncg >> 9, nc = ncg & 511;
        unsigned short* op = obf + (size_t)mat * MATSTR + (size_t)m * 512 + nc;
        uint4 o0, o1;
        o0.x = (unsigned)f2b(v[0]) | ((unsigned)f2b(v[1]) << 16);
        o0.y = (unsigned)f2b(v[2]) | ((unsigned)f2b(v[3]) << 16);
        o0.z = (unsigned)f2b(v[4]) | ((unsigned)f2b(v[5]) << 16);
        o0.w = (unsigned)f2b(v[6]) | ((unsigned)f2b(v[7]) << 16);
        o1.x = (unsigned)f2b(v[8]) | ((unsigned)f2b(v[9]) << 16);
        o1.y = (unsigned)f2b(v[10]) | ((unsigned)f2b(v[11]) << 16);
        o1.z = (unsigned)f2b(v[12]) | ((unsigned)f2b(v[13]) << 16);
        o1.w = (unsigned)f2b(v[14]) | ((unsigned)f2b(v[15]) << 16);
        *(uint4*)op = o0; *(uint4*)(op + 8) = o1;
      } else if (mode == 1) {
        const int nc = n0 + h * 64 + c0;
        const float tr = trust[m];
        float wv[16], av[16];
        *(float4*)(wv)      = *(const float4*)(wg512 + nc);
        *(float4*)(wv + 4)  = *(const float4*)(wg512 + nc + 4);
        *(float4*)(wv + 8)  = *(const float4*)(wg512 + nc + 8);
        *(float4*)(wv + 12) = *(const float4*)(wg512 + nc + 12);
        const float* app = Afp + (size_t)m * 512 + nc;
        *(float4*)(av)      = *(const float4*)(app);
        *(float4*)(av + 4)  = *(const float4*)(app + 4);
        *(float4*)(av + 8)  = *(const float4*)(app + 8);
        *(float4*)(av + 12) = *(const float4*)(app + 12);
        #pragma unroll
        for (int e = 0; e < 16; e++) v[e] = av[e] * sigm(v[e] + tr * wv[e]);
        unsigned short* op = obf + (size_t)m * 512 + nc;
        uint4 o0, o1;
        o0.x = (unsigned)f2b(v[0]) | ((unsigned)f2b(v[1]) << 16);
        o0.y = (unsigned)f2b(v[2]) | ((unsigned)f2b(v[3]) << 16);
        o0.z = (unsigned)f2b(v[4]) | ((unsigned)f2b(v[5]) << 16);
        o0.w = (unsigned)f2b(v[6]) | ((unsigned)f2b(v[7]) << 16);
        o1.x = (unsigned)f2b(v[8]) | ((unsigned)f2b(v[9]) << 16);
        o1.y = (unsigned)f2b(v[10]) | ((unsigned)f2b(v[11]) << 16);
        o1.z = (unsigned)f2b(v[12]) | ((unsigned)f2b(v[13]) << 16);
        o1.w = (unsigned)f2b(v[14]) | ((unsigned)f2b(v[15]) << 16);
        *(uint4*)op = o0; *(uint4*)(op + 8) = o1;
      } else {
        const int nc = n0 + h * 64 + c0;
        float* op = ofp + (size_t)m * 512 + nc;
        *(float4*)(op)      = *(const float4*)(v);
        *(float4*)(op + 4)  = *(const float4*)(v + 4);
        *(float4*)(op + 8)  = *(const float4*)(v + 8);
        *(float4*)(op + 12) = *(const float4*)(v + 12);
      }
    }
  }
}

// ---------------------------------------------------------------------------
// Fused attention: block = (bh, 16 q-rows), 512 thr (8 waves), 2 blocks/CU.
// Wave w owns k-slice [w*256, w*256+256) for QK^T and PV.
// pb: 16x2048 bf16, XOR-swizzled (byte ^= (row&7)<<4) -> conflict-minimal.
// ---------------------------------------------------------------------------
__global__ __launch_bounds__(512) void k_attn(
    const unsigned short* __restrict__ Qb, const unsigned short* __restrict__ Kb,
    const unsigned short* __restrict__ Vt, const float* __restrict__ trust,
    const float* __restrict__ ts, float* __restrict__ attn,
    float* __restrict__ attf, unsigned short* __restrict__ attb) {
  __shared__ unsigned short pb[16 * 2048];   // 64KB, swizzled
  __shared__ float tks[2048];
  __shared__ float attS[16][72];
  __shared__ float Lsum[16];
  __shared__ float invLs[16];

  const int t = threadIdx.x;
  const int q0 = blockIdx.x * 16;
  const int bh = blockIdx.y, b = bh >> 3, h = bh & 7;
  const int w = t >> 6, lane = t & 63, g = lane >> 4, ln = lane & 15;
  const int kslice = w * 256;

  *(float4*)(tks + t * 4) = *(const float4*)(trust + b * SEQ + t * 4);
  if (t < 16) Lsum[t] = 0.f;
  for (int i = t; i < 16 * 72; i += 512) ((float*)attS)[i] = 0.f;
  const float sa = ts[0], sbb = ts[1], scc = ts[2];
  __syncthreads();

  // ---- QK^T swapped: mfma(K, Q) -> lane holds 4 consecutive keys, q = ln ----
  const unsigned short* qrow = Qb + ((size_t)(b * SEQ + q0 + ln)) * 512 + h * 64;
  const bf16x8 qf0 = *(const bf16x8*)(qrow + g * 8);
  const bf16x8 qf1 = *(const bf16x8*)(qrow + 32 + g * 8);
  const float tq = tks[q0 + ln];
  float rsum = 0.f;
  const int swq = (ln & 7) << 4;
  char* prowq = (char*)pb + ln * 4096;

  #pragma unroll 2
  for (int kt = 0; kt < 16; kt++) {
    const int kb = kslice + kt * 16;
    const unsigned short* krow = Kb + ((size_t)(b * SEQ + kb + ln)) * 512 + h * 64;
    const bf16x8 kf0 = *(const bf16x8*)(krow + g * 8);
    const bf16x8 kf1 = *(const bf16x8*)(krow + 32 + g * 8);
    f32x4 acc = (f32x4){0.f, 0.f, 0.f, 0.f};
    acc = MFMA(kf0, qf0, acc, 0, 0, 0);
    acc = MFMA(kf1, qf1, acc, 0, 0, 0);
    unsigned short po[4];
    #pragma unroll
    for (int r = 0; r < 4; r++) {
      const float tk = tks[kb + g * 4 + r];
      const float y = 0.1f * sigm(sa * tq * tk + sbb * (tq + tk) + scc);
      const float p = __expf(acc[r] * 0.125f) * (1.f + y + 0.5f * y * y);
      rsum += p;
      po[r] = f2b(p);
    }
    *(uint2*)(prowq + (((kb + g * 4) * 2) ^ swq)) = *(uint2*)po;
  }
  rsum += __shfl_xor(rsum, 16);
  rsum += __shfl_xor(rsum, 32);
  if (lane < 16) atomicAdd(&Lsum[ln], rsum);
  __syncthreads();
  if (t < 16) invLs[t] = 1.f / Lsum[t];
  __syncthreads();

  // ---- write attn = p * invL (stores overlap the PV phase below) ----
  {
    const int row = t >> 5, lr = t & 31;
    const float il = invLs[row];
    float* dst = attn + ((size_t)bh * SEQ + q0 + row) * SEQ;
    const char* src = (const char*)pb + row * 4096;
    const int sw = (row & 7) << 4;
    #pragma unroll 4
    for (int it = 0; it < 16; it++) {
      const int colb = it * 256 + lr * 8;
      const uint2 v = *(const uint2*)(src + (colb ^ sw));
      float4 o;
      o.x = b2f(v.x & 0xffffu) * il; o.y = b2f(v.x >> 16) * il;
      o.z = b2f(v.y & 0xffffu) * il; o.w = b2f(v.y >> 16) * il;
      *(float4*)(dst + it * 128 + lr * 4) = o;
    }
  }

  // ---- PV: attended^T = mfma(Vt, P^T); wave covers its k-slice, all 64 d ----
  {
    f32x4 pacc[4];
    #pragma unroll
    for (int dt = 0; dt < 4; dt++) pacc[dt] = (f32x4){0.f, 0.f, 0.f, 0.f};
    const char* prow = (const char*)pb + ln * 4096;
    const int sw = (ln & 7) << 4;
    #pragma unroll 2
    for (int ks = 0; ks < 8; ks++) {
      const int kb = kslice + ks * 32;
      const bf16x8 pf = *(const bf16x8*)(prow + ((kb * 2 + g * 16) ^ sw));
      #pragma unroll
      for (int dt = 0; dt < 4; dt++) {
        const bf16x8 vf =
            *(const bf16x8*)(Vt + ((size_t)(bh * 64 + dt * 16 + ln)) * SEQ + kb + g * 8);
        pacc[dt] = MFMA(vf, pf, pacc[dt], 0, 0, 0);
      }
    }
    #pragma unroll
    for (int dt = 0; dt < 4; dt++)
      #pragma unroll
      for (int r = 0; r < 4; r++)
        atomicAdd(&attS[ln][dt * 16 + g * 4 + r], pacc[dt][r]);
  }
  __syncthreads();

  if (t < 256) {
    const int row = t >> 4, d0 = (t & 15) * 4;
    const float il = invLs[row];
    float4 v = *(const float4*)&attS[row][d0];
    v.x *= il; v.y *= il; v.z *= il; v.w *= il;
    const size_t gb = ((size_t)(b * SEQ + q0 + row)) * 512 + h * 64 + d0;
    *(float4*)(attf + gb) = v;
    uint2 o;
    o.x = (unsigned)f2b(v.x) | ((unsigned)f2b(v.y) << 16);
    o.y = (unsigned)f2b(v.z) | ((unsigned)f2b(v.w) << 16);
    *(uint2*)(attb + gb) = o;
  }
}

// ---------------------------------------------------------------------------
extern "C" void kernel_launch(void* const* d_in, const int* in_sizes, int n_in,
                              void* d_out, int out_size, void* d_ws, size_t ws_size,
                              hipStream_t stream) {
  const float* x     = (const float*)d_in[0];
  const float* trust = (const float*)d_in[1];
  const float* Wq = (const float*)d_in[2];  const float* bq = (const float*)d_in[3];
  const float* Wk = (const float*)d_in[4];  const float* bk = (const float*)d_in[5];
  const float* Wv = (const float*)d_in[6];  const float* bv = (const float*)d_in[7];
  const float* Wt = (const float*)d_in[8];  const float* bt = (const float*)d_in[9];
  const float* Wg = (const float*)d_in[10]; const float* bg = (const float*)d_in[11];
  const float* Wo = (const float*)d_in[12]; const float* bo = (const float*)d_in[13];

  float* out  = (float*)d_out;
  float* attn = out + OUT_ATTN;
  char* ws = (char*)d_ws;

  unsigned short* Vtb  = (unsigned short*)(ws + OFF_VT);
  unsigned short* Qb   = (unsigned short*)(ws + OFF_QB);   // Q|K|V contiguous
  unsigned short* Kb   = (unsigned short*)(ws + OFF_KB);
  unsigned short* Vb   = (unsigned short*)(ws + OFF_VB);
  unsigned short* attb = (unsigned short*)(ws + OFF_VB);   // V dead after vtrans
  unsigned short* gatb = (unsigned short*)(ws + OFF_KB);   // K dead after attn
  float* attf = (float*)(ws + OFF_ATTF);
  unsigned short* Wqt = (unsigned short*)(ws + OFF_WQT);
  unsigned short* Wkt = Wqt + 512 * 512;
  unsigned short* Wvt = Wkt + 512 * 512;
  unsigned short* Wgt = Wvt + 512 * 512;
  unsigned short* Wot = Wgt + 512 * 512;
  float* bcat = (float*)(ws + OFF_BCAT);
  float* tsp  = (float*)(ws + OFF_TS);

  k_prep<<<1, 512, 0, stream>>>(Wt, bt, bq, bk, bv, bcat, tsp);
  dim3 wg(8, 8);
  k_wtrans<<<wg, 256, 0, stream>>>(Wq, Wqt);
  k_wtrans<<<wg, 256, 0, stream>>>(Wk, Wkt);
  k_wtrans<<<wg, 256, 0, stream>>>(Wv, Wvt);
  k_wtrans<<<wg, 256, 0, stream>>>(Wg, Wgt);   // first 512 rows of Wg
  k_wtrans<<<wg, 256, 0, stream>>>(Wo, Wot);

  // fused QKV: N = 1536
  k_gemm<<<dim3(128, 12), 256, 0, stream>>>(x, nullptr, Wqt, bcat, nullptr,
                                            nullptr, nullptr, Qb, nullptr, 0);

  k_vtrans<<<dim3(32, 32), 256, 0, stream>>>(Vb, Vtb);

  k_attn<<<dim3(128, 32), 512, 0, stream>>>(Qb, Kb, Vtb, trust, tsp,
                                            attn, attf, attb);

  k_gemm<<<dim3(128, 4), 256, 0, stream>>>(nullptr, attb, Wgt, bg, Wg + 512 * 512,
                                           trust, attf, gatb, nullptr, 1);
  k_gemm<<<dim3(128, 4), 256, 0, stream>>>(nullptr, gatb, Wot, bo, nullptr,
                                           nullptr, nullptr, nullptr, out, 2);
}